// Round 1
// 1387.446 us; speedup vs baseline: 1.0304x; 1.0304x over previous
//
#include <hip/hip_runtime.h>

#define D_K 768
#define M_ROWS 4096
#define V_COLS 50257

// ---- GEMM geometry ----
#define BM 256
#define BN 256
#define BK 32
#define NT (D_K / BK)            // 24 K-tiles
#define NBUF 4                   // 4-deep LDS pipeline, 128 KiB total
#define M_TILES (M_ROWS / BM)    // 16
#define N_TILES ((V_COLS + BN - 1) / BN)  // 197
#define GRID (M_TILES * N_TILES) // 3152 = 8 * 394
#define CPX (GRID / 8)           // 394 (exact -> bijective XCD swizzle)
#define BUF_SHORTS (BM * BK)     // 8192 shorts = 16 KiB per operand buffer
#define SMEM_BYTES (2 * NBUF * BUF_SHORTS * 2)  // 131072

typedef __attribute__((ext_vector_type(8))) __bf16 bf16x8;
typedef __attribute__((ext_vector_type(4))) float f32x4;

__device__ __forceinline__ unsigned short f2bf(float f) {
    unsigned int u = __float_as_uint(f);
    unsigned int r = (u + 0x7fffu + ((u >> 16) & 1u)) >> 16;
    return (unsigned short)r;
}

#define GLOAD_LDS16(g, l)                                                     \
    __builtin_amdgcn_global_load_lds(                                         \
        (const __attribute__((address_space(1))) void*)(g),                   \
        (__attribute__((address_space(3))) void*)(l), 16, 0, 0)

// ---------------- Kernel 1: gather + RMSNorm -> bf16 A ----------------
__global__ __launch_bounds__(256) void gather_norm(
    const int* __restrict__ seq, const float* __restrict__ emb,
    const float* __restrict__ w, unsigned short* __restrict__ outA) {
    const int r = blockIdx.x;      // 0..4095
    const int t = threadIdx.x;     // 0..255
    const int idx = seq[r];
    const float* src = emb + (size_t)idx * D_K;
    float x0 = src[t], x1 = src[t + 256], x2 = src[t + 512];
    float ss = x0 * x0 + x1 * x1 + x2 * x2;
    #pragma unroll
    for (int o = 32; o; o >>= 1) ss += __shfl_down(ss, o, 64);
    __shared__ float red[4];
    if ((t & 63) == 0) red[t >> 6] = ss;
    __syncthreads();
    float tot = red[0] + red[1] + red[2] + red[3];
    float scale = rsqrtf(tot * (1.0f / (float)D_K) + 1e-5f);
    unsigned short* dst = outA + (size_t)r * D_K;
    dst[t]       = f2bf(x0 * scale * w[t]);
    dst[t + 256] = f2bf(x1 * scale * w[t + 256]);
    dst[t + 512] = f2bf(x2 * scale * w[t + 512]);
}

// ---------------- Kernel 2: fp32 -> bf16 convert of W ----------------
__global__ __launch_bounds__(256) void convert_w(
    const float* __restrict__ w, unsigned short* __restrict__ out, int n4) {
    int i = blockIdx.x * 256 + threadIdx.x;
    if (i < n4) {
        float4 v = ((const float4*)w)[i];
        ushort4 o;
        o.x = f2bf(v.x); o.y = f2bf(v.y); o.z = f2bf(v.z); o.w = f2bf(v.w);
        ((ushort4*)out)[i] = o;
    }
}

// ---------------- Kernel 3: C[M,V] = A[M,K] * W[V,K]^T (bf16 MFMA) ----------------
// 256x256 tile, 8 waves (2Mx4N, 128x64 each), BK=32, 4-deep counted-vmcnt
// pipeline (T4), XOR-swizzled LDS (T2), XCD-swizzled blockIdx (T1),
// setprio around MFMA (T5).
__global__ __launch_bounds__(512, 2) void gemm_nt(
    const unsigned short* __restrict__ A, const unsigned short* __restrict__ Bw,
    float* __restrict__ C) {
    extern __shared__ unsigned short smem[];
    unsigned short* As = smem;                      // [NBUF][256][32]
    unsigned short* Bs = smem + NBUF * BUF_SHORTS;  // [NBUF][256][32]

    const int tid = threadIdx.x;
    const int lane = tid & 63;
    const int w = tid >> 6;

    // T1: bijective XCD swizzle (GRID % 8 == 0), m-fastest within chunk.
    const int bid = blockIdx.x;
    const int swz = (bid & 7) * CPX + (bid >> 3);
    const int m_tile = swz & 15;
    const int n_tile = swz >> 4;

    // ---- staging setup ----
    // dest chunk o = tid (rows 0..127) / tid+512 (rows 128..255); linear LDS.
    // T2: source chunk = c ^ ((row>>1)&3)  (16B-chunk XOR swizzle, rule 21:
    // inverse-swizzled global source + linear gload_lds dest).
    const int srow = tid >> 2;                      // 0..127
    const int cs = (tid & 3) ^ ((tid >> 3) & 3);    // swizzled source chunk
    const int a_row0 = m_tile * BM + srow;
    int b_row0 = n_tile * BN + srow;
    int b_row1 = b_row0 + 128;
    b_row0 = min(b_row0, V_COLS - 1);               // tail tile: dup last row,
    b_row1 = min(b_row1, V_COLS - 1);               // masked at store
    const unsigned short* gA0 = A + (size_t)a_row0 * D_K + cs * 8;
    const unsigned short* gA1 = gA0 + (size_t)128 * D_K;
    const unsigned short* gB0 = Bw + (size_t)b_row0 * D_K + cs * 8;
    const unsigned short* gB1 = Bw + (size_t)b_row1 * D_K + cs * 8;
    unsigned short* dA0 = As + tid * 8;
    unsigned short* dA1 = As + (tid + 512) * 8;
    unsigned short* dB0 = Bs + tid * 8;
    unsigned short* dB1 = Bs + (tid + 512) * 8;

#define STAGE(t) do {                                                         \
        const int _o = (t) * BK;                                              \
        const int _b = ((t) & (NBUF - 1)) * BUF_SHORTS;                       \
        GLOAD_LDS16(gA0 + _o, dA0 + _b);                                      \
        GLOAD_LDS16(gA1 + _o, dA1 + _b);                                      \
        GLOAD_LDS16(gB0 + _o, dB0 + _b);                                      \
        GLOAD_LDS16(gB1 + _o, dB1 + _b);                                      \
    } while (0)

    // ---- compute setup ----
    const int wr = w >> 2;          // 0..1
    const int wc = w & 3;           // 0..3
    const int wm = wr * 128;
    const int wn = wc * 64;
    const int fr = lane & 15;
    // read-side swizzle: chunk = kc ^ ((row>>1)&3); (row>>1)&3 == (fr>>1)&3
    // for all frag rows (wm, wn, mi*16 contribute multiples of 8).
    const int kcs = (lane >> 4) ^ ((fr >> 1) & 3);
    const int aOff = (wm + fr) * BK + kcs * 8;
    const int bOff = (wn + fr) * BK + kcs * 8;

    f32x4 acc[8][4];
    #pragma unroll
    for (int mi = 0; mi < 8; mi++)
        #pragma unroll
        for (int ni = 0; ni < 4; ni++) acc[mi][ni] = (f32x4){0.f, 0.f, 0.f, 0.f};

    // prologue: 3 K-tiles in flight
    STAGE(0); STAGE(1); STAGE(2);

    for (int t = 0; t < NT; ++t) {
        if (t < NT - 3) {
            STAGE(t + 3);
            // T4: counted wait — 3 tiles x 4 loads stay in flight, tile t done.
            asm volatile("s_waitcnt vmcnt(12)" ::: "memory");
        } else if (t == NT - 3) {
            asm volatile("s_waitcnt vmcnt(8)" ::: "memory");
        } else if (t == NT - 2) {
            asm volatile("s_waitcnt vmcnt(4)" ::: "memory");
        } else {
            asm volatile("s_waitcnt vmcnt(0)" ::: "memory");
        }
        __builtin_amdgcn_s_barrier();
        asm volatile("" ::: "memory");

        const int boff = (t & (NBUF - 1)) * BUF_SHORTS;
        const unsigned short* pa = As + boff + aOff;
        const unsigned short* pb = Bs + boff + bOff;
        bf16x8 a[8], b[4];
        #pragma unroll
        for (int mi = 0; mi < 8; mi++)
            a[mi] = *(const bf16x8*)(pa + mi * (16 * BK));
        #pragma unroll
        for (int ni = 0; ni < 4; ni++)
            b[ni] = *(const bf16x8*)(pb + ni * (16 * BK));

        __builtin_amdgcn_s_setprio(1);
        #pragma unroll
        for (int mi = 0; mi < 8; mi++)
            #pragma unroll
            for (int ni = 0; ni < 4; ni++)
                acc[mi][ni] = __builtin_amdgcn_mfma_f32_16x16x32_bf16(
                    a[mi], b[ni], acc[mi][ni], 0, 0, 0);
        __builtin_amdgcn_s_setprio(0);

        asm volatile("" ::: "memory");
        __builtin_amdgcn_s_barrier();   // reads of buf done before its re-stage
    }
#undef STAGE

    // epilogue: C/D layout col = lane&15, row = (lane>>4)*4 + j (verified)
    const int crow0 = m_tile * BM + wm + ((lane >> 4) << 2);
    const int ccol0 = n_tile * BN + wn + fr;
    if (n_tile < N_TILES - 1) {
        #pragma unroll
        for (int mi = 0; mi < 8; mi++)
            #pragma unroll
            for (int j = 0; j < 4; j++) {
                float* Crow = C + (size_t)(crow0 + mi * 16 + j) * V_COLS + ccol0;
                #pragma unroll
                for (int ni = 0; ni < 4; ni++) Crow[ni * 16] = acc[mi][ni][j];
            }
    } else {
        #pragma unroll
        for (int mi = 0; mi < 8; mi++)
            #pragma unroll
            for (int j = 0; j < 4; j++) {
                float* Crow = C + (size_t)(crow0 + mi * 16 + j) * V_COLS;
                #pragma unroll
                for (int ni = 0; ni < 4; ni++) {
                    const int c = ccol0 + ni * 16;
                    if (c < V_COLS) Crow[c] = acc[mi][ni][j];
                }
            }
    }
}

extern "C" void kernel_launch(void* const* d_in, const int* in_sizes, int n_in,
                              void* d_out, int out_size, void* d_ws, size_t ws_size,
                              hipStream_t stream) {
    const int* seq = (const int*)d_in[0];           // [2,2048] int32
    const float* emb = (const float*)d_in[1];       // [50257,768] f32
    const float* norm_w = (const float*)d_in[2];    // [768] f32
    const float* out_emb = (const float*)d_in[3];   // [50257,768] f32
    float* out = (float*)d_out;                     // [4096,50257] f32

    unsigned short* A_bf = (unsigned short*)d_ws;                    // 4096*768*2
    unsigned short* W_bf = (unsigned short*)((char*)d_ws + 6291456); // 50257*768*2

    static int smem_configured = 0;
    if (!smem_configured) {
        (void)hipFuncSetAttribute((const void*)gemm_nt,
                                  hipFuncAttributeMaxDynamicSharedMemorySize,
                                  SMEM_BYTES);
        smem_configured = 1;
    }

    gather_norm<<<M_ROWS, 256, 0, stream>>>(seq, emb, norm_w, A_bf);

    const int n4 = V_COLS * D_K / 4;
    convert_w<<<(n4 + 255) / 256, 256, 0, stream>>>(out_emb, W_bf, n4);

    gemm_nt<<<GRID, 512, SMEM_BYTES, stream>>>(A_bf, W_bf, out);
}